// Round 4
// baseline (4110.784 us; speedup 1.0000x reference)
//
#include <hip/hip_runtime.h>
#include <hip/hip_bf16.h>
#include <stdint.h>

// ---------------------------------------------------------------------------
// 2-layer GRU, B=64 S=2048 IN=208 H=100 OUT=98.
//   1) gemm_bias: xg0 = seq @ w_ih_l0^T + b_ih_l0        (fp32 GEMM)
//   2) gru_fused: BOTH GRU layers in one persistent kernel, one block/batch.
//      L1 lags L0 by one step; xg1 = w_ih1 @ y0 computed on the fly.
//   3) gemm_bias: out = y1 @ w_out^T + b_out             (fp32 GEMM)
// ---------------------------------------------------------------------------

typedef __fp16 half2v __attribute__((ext_vector_type(2)));   // matches V2h builtin type

__device__ __forceinline__ float fsig(float x)  { return 1.f / (1.f + __expf(-x)); }
__device__ __forceinline__ float ftanh(float x) { return 1.f - 2.f / (1.f + __expf(2.f * x)); }

__device__ __forceinline__ uint32_t pkh2(float a, float b) {
    half2v h = __builtin_amdgcn_cvt_pkrtz(a, b);
    return __builtin_bit_cast(uint32_t, h);
}

__device__ __forceinline__ float dot2acc(uint32_t w, uint32_t h, float acc) {
#if __has_builtin(__builtin_amdgcn_fdot2)
    return __builtin_amdgcn_fdot2(__builtin_bit_cast(half2v, w),
                                  __builtin_bit_cast(half2v, h), acc, false);
#else
    half2v wv = __builtin_bit_cast(half2v, w), hv = __builtin_bit_cast(half2v, h);
    return acc + (float)wv.x * (float)hv.x + (float)wv.y * (float)hv.y;
#endif
}

// per-component GRU gate update on a float4 quad
__device__ __forceinline__ void gru4(float4& h, float4 xr, float4 xz, float4 xn,
                                     float4 hr, float4 hz, float4 hn) {
    float r, z, n;
    r = fsig(xr.x + hr.x); z = fsig(xz.x + hz.x); n = ftanh(xn.x + r * hn.x); h.x = (1.f - z) * n + z * h.x;
    r = fsig(xr.y + hr.y); z = fsig(xz.y + hz.y); n = ftanh(xn.y + r * hn.y); h.y = (1.f - z) * n + z * h.y;
    r = fsig(xr.z + hr.z); z = fsig(xz.z + hz.z); n = ftanh(xn.z + r * hn.z); h.z = (1.f - z) * n + z * h.z;
    r = fsig(xr.w + hr.w); z = fsig(xz.w + hz.w); n = ftanh(xn.w + r * hn.w); h.w = (1.f - z) * n + z * h.w;
}

// ---------------------------------------------------------------------------
// Fused 2-layer scan. Grid = 64 blocks (one batch each), 1024 threads.
// Gate slots: [0,300)=L0 hh (hs0); [300,600)=L1 ih (hs0 = y0 lagged);
//             [640,940)=L1 hh (hs1). Hole threads (600-639, 940-959) run a
// dummy dot (valid weight row) so every lane of waves 0-14 is ACTIVE —
// required because readlane ignores exec and reads lanes 0..49 of hp.
// Wave 15 = updater (25 L0 quad-lanes + 25 L1 quad-lanes).
// ---------------------------------------------------------------------------
__global__ __launch_bounds__(1024, 4)
void gru_fused(const float* __restrict__ xg0,    // (B,Sc,300), b_ih0 already added
               const float* __restrict__ w_hh0, const float* __restrict__ b_hh0,
               const float* __restrict__ w_ih1, const float* __restrict__ b_ih1,
               const float* __restrict__ w_hh1, const float* __restrict__ b_hh1,
               const float* __restrict__ h_init,  // (2,B,100)
               float* __restrict__ h_state,       // (2,B,100) persistent in ws
               float* __restrict__ y1,            // (B,Sc,100)
               int Sc, int first)
{
    __shared__ __align__(16) float res[960];     // gate pre-activations
    __shared__ uint32_t hs0p[64];                // h0 as 50 packed f16 pairs
    __shared__ uint32_t hs1p[64];

    const int tid = threadIdx.x, b = blockIdx.x;
    const int lane = tid & 63;
    const bool is_upd = (tid >= 960);            // wave 15 (wave-uniform)

    // ---- dot-thread setup: one weight row as 50 packed f16 pairs ----
    const float* wrow = w_hh0;                   // dummy valid row for hole/updater lanes
    float bias = 0.f;
    bool store_ok = false;
    if (tid < 300)                    { wrow = w_hh0 + tid * 100;         bias = b_hh0[tid];       store_ok = true; }
    else if (tid < 600)               { wrow = w_ih1 + (tid - 300) * 100; bias = b_ih1[tid - 300]; store_ok = true; }
    else if (tid >= 640 && tid < 940) { wrow = w_hh1 + (tid - 640) * 100; bias = b_hh1[tid - 640]; store_ok = true; }

    uint32_t w[50];
    #pragma unroll
    for (int i = 0; i < 25; i++) {
        float4 v = ((const float4*)wrow)[i];
        w[2 * i]     = pkh2(v.x, v.y);
        w[2 * i + 1] = pkh2(v.z, v.w);
    }
    const uint32_t* hsrc = (tid < 640) ? hs0p : hs1p;   // wave-uniform select

    // ---- updater setup: wave 15, quads of h in fp32 registers ----
    int role = -1, qi = 0;
    if (is_upd) {
        if (lane < 25)                    { role = 0; qi = lane; }
        else if (lane >= 32 && lane < 57) { role = 1; qi = lane - 32; }
    }
    float4 h = make_float4(0.f, 0.f, 0.f, 0.f);
    if (role >= 0) {
        const float* hsg = (first ? h_init : h_state) + role * 6400 + b * 100;
        h = ((const float4*)hsg)[qi];
        uint32_t* hp = (role == 0) ? hs0p : hs1p;
        hp[2 * qi]     = pkh2(h.x, h.y);
        hp[2 * qi + 1] = pkh2(h.z, h.w);
    }
    const float* xrow_base = xg0 + (size_t)b * Sc * 300;
    float4 c0, c1, c2, n0, n1, n2;                // current / next xg0 row quads
    if (role == 0) {
        c0 = ((const float4*)xrow_base)[qi];
        c1 = ((const float4*)xrow_base)[25 + qi];
        c2 = ((const float4*)xrow_base)[50 + qi];
    }
    __syncthreads();

    for (int t = 0; t <= Sc; t++) {
        // ---- dot phase (waves 0..14, ALL lanes active); wave-15 prefetches xg0 ----
        if (!is_upd) {
            uint32_t hp = hsrc[lane];             // 1 ds_read_b32 per wave, all lanes defined
            float a0 = bias, a1 = 0.f;
            #pragma unroll
            for (int k = 0; k < 50; k += 2) {
                uint32_t h0b = (uint32_t)__builtin_amdgcn_readlane((int)hp, k);
                a0 = dot2acc(w[k], h0b, a0);
                uint32_t h1b = (uint32_t)__builtin_amdgcn_readlane((int)hp, k + 1);
                a1 = dot2acc(w[k + 1], h1b, a1);
            }
            if (store_ok) res[tid] = a0 + a1;
        } else if (role == 0) {
            const float* nr = xrow_base + (size_t)min(t + 1, Sc - 1) * 300;
            n0 = ((const float4*)nr)[qi];
            n1 = ((const float4*)nr)[25 + qi];
            n2 = ((const float4*)nr)[50 + qi];
        }
        __syncthreads();

        // ---- update phase (wave 15 only) ----
        if (role == 0 && t < Sc) {
            const float4* r4 = (const float4*)res;
            float4 hr = r4[qi], hz = r4[25 + qi], hn = r4[50 + qi];
            gru4(h, c0, c1, c2, hr, hz, hn);
            hs0p[2 * qi]     = pkh2(h.x, h.y);
            hs0p[2 * qi + 1] = pkh2(h.z, h.w);
            c0 = n0; c1 = n1; c2 = n2;
        }
        if (role == 1 && t >= 1) {
            const float4* r4 = (const float4*)res;
            float4 xr = r4[75 + qi],  xz = r4[100 + qi], xn = r4[125 + qi];
            float4 hr = r4[160 + qi], hz = r4[185 + qi], hn = r4[210 + qi];
            gru4(h, xr, xz, xn, hr, hz, hn);
            hs1p[2 * qi]     = pkh2(h.x, h.y);
            hs1p[2 * qi + 1] = pkh2(h.z, h.w);
            ((float4*)(y1 + ((size_t)b * Sc + (t - 1)) * 100))[qi] = h;
        }
        __syncthreads();
    }

    if (role >= 0)
        ((float4*)(h_state + role * 6400 + b * 100))[qi] = h;
}

// ---------------------------------------------------------------------------
// fp32 tiled GEMM with bias: C[row,n] = sum_k A[row,k]*W[n,k] + bias[n]
// ---------------------------------------------------------------------------
#define GB_BM 64
#define GB_BN 64
#define GB_BK 16

__global__ __launch_bounds__(256)
void gemm_bias(const float* __restrict__ A, const float* __restrict__ W,
               const float* __restrict__ bias, float* __restrict__ C,
               int Sc, long a_bs, long a_ss, long c_bs, long c_ss,
               int N, int K)
{
    __shared__ float As[GB_BK][68];
    __shared__ float Bs[GB_BK][68];
    const int tid = threadIdx.x;
    const int m0 = blockIdx.x * GB_BM;
    const int n0 = blockIdx.y * GB_BN;

    const int lm = tid >> 2;
    const int lk = (tid & 3) << 2;
    const int row = m0 + lm;
    const float* arow = A + (long)(row / Sc) * a_bs + (long)(row % Sc) * a_ss;
    const int wrow = n0 + lm;
    const float* wrp = W + (long)wrow * K;
    const bool wv_ok = (wrow < N);

    const int tx = tid & 15;
    const int ty = tid >> 4;

    float acc[4][4] = {};

    for (int k0 = 0; k0 < K; k0 += GB_BK) {
        float4 av, bv;
        if (k0 + GB_BK <= K) {
            av = *(const float4*)(arow + k0 + lk);
            bv = wv_ok ? *(const float4*)(wrp + k0 + lk) : make_float4(0.f,0.f,0.f,0.f);
        } else {
            av = make_float4(0.f,0.f,0.f,0.f);
            bv = make_float4(0.f,0.f,0.f,0.f);
            const int kb = k0 + lk;
            if (kb + 0 < K) { av.x = arow[kb+0]; if (wv_ok) bv.x = wrp[kb+0]; }
            if (kb + 1 < K) { av.y = arow[kb+1]; if (wv_ok) bv.y = wrp[kb+1]; }
            if (kb + 2 < K) { av.z = arow[kb+2]; if (wv_ok) bv.z = wrp[kb+2]; }
            if (kb + 3 < K) { av.w = arow[kb+3]; if (wv_ok) bv.w = wrp[kb+3]; }
        }
        As[lk+0][lm] = av.x; As[lk+1][lm] = av.y; As[lk+2][lm] = av.z; As[lk+3][lm] = av.w;
        Bs[lk+0][lm] = bv.x; Bs[lk+1][lm] = bv.y; Bs[lk+2][lm] = bv.z; Bs[lk+3][lm] = bv.w;
        __syncthreads();
        #pragma unroll
        for (int kk = 0; kk < GB_BK; kk++) {
            float4 a  = *(const float4*)&As[kk][ty << 2];
            float4 bb = *(const float4*)&Bs[kk][tx << 2];
            float ar[4] = {a.x, a.y, a.z, a.w};
            float br[4] = {bb.x, bb.y, bb.z, bb.w};
            #pragma unroll
            for (int i = 0; i < 4; i++)
                #pragma unroll
                for (int j = 0; j < 4; j++)
                    acc[i][j] += ar[i] * br[j];
        }
        __syncthreads();
    }

    #pragma unroll
    for (int i = 0; i < 4; i++) {
        const int r = m0 + (ty << 2) + i;
        float* crow = C + (long)(r / Sc) * c_bs + (long)(r % Sc) * c_ss;
        #pragma unroll
        for (int j = 0; j < 4; j++) {
            const int col = n0 + (tx << 2) + j;
            if (col < N) crow[col] = acc[i][j] + bias[col];
        }
    }
}

// ---------------------------------------------------------------------------

extern "C" void kernel_launch(void* const* d_in, const int* in_sizes, int n_in,
                              void* d_out, int out_size, void* d_ws, size_t ws_size,
                              hipStream_t stream)
{
    const float* seq    = (const float*)d_in[0];
    const float* h0     = (const float*)d_in[1];   // (2, 64, 100)
    const float* w_ih0  = (const float*)d_in[2];   // (300, 208)
    const float* w_hh0  = (const float*)d_in[3];   // (300, 100)
    const float* b_ih0  = (const float*)d_in[4];
    const float* b_hh0  = (const float*)d_in[5];
    const float* w_ih1  = (const float*)d_in[6];   // (300, 100)
    const float* w_hh1  = (const float*)d_in[7];
    const float* b_ih1  = (const float*)d_in[8];
    const float* b_hh1  = (const float*)d_in[9];
    const float* w_out  = (const float*)d_in[10];  // (98, 100)
    const float* b_out  = (const float*)d_in[11];
    float* out = (float*)d_out;

    const int B = 64, S = 2048, IN = 208, H = 100, G = 300, OUT = 98;

    // largest power-of-2 chunk Sc whose buffers fit the workspace
    int Sc = S;
    while (Sc > 16) {
        size_t need = ((size_t)B * Sc * (G + H) + 2 * (size_t)B * H) * sizeof(float);
        if (need <= ws_size) break;
        Sc >>= 1;
    }
    const int NC = S / Sc;

    float* h_state = (float*)d_ws;                    // (2,B,100)
    float* y1c     = h_state + 2 * (size_t)B * H;     // (B,Sc,100)
    float* xgc     = y1c + (size_t)B * Sc * H;        // (B,Sc,300)

    const dim3 blk(256);
    const dim3 gX((B * Sc) / GB_BM, (G + GB_BN - 1) / GB_BN);
    const dim3 gO((B * Sc) / GB_BM, (OUT + GB_BN - 1) / GB_BN);

    for (int c = 0; c < NC; c++) {
        const int s0 = c * Sc;
        const int first = (c == 0);

        // 1) xg0 = seq @ w_ih0^T + b_ih0
        gemm_bias<<<gX, blk, 0, stream>>>(seq + (long)s0 * IN, w_ih0, b_ih0, xgc,
                                          Sc, (long)S * IN, (long)IN,
                                          (long)Sc * G, (long)G, G, IN);
        // 2) fused 2-layer scan (y0 never leaves LDS; xg1 on the fly)
        gru_fused<<<dim3(B), dim3(1024), 0, stream>>>(xgc,
                                                      w_hh0, b_hh0, w_ih1, b_ih1,
                                                      w_hh1, b_hh1,
                                                      h0, h_state, y1c, Sc, first);
        // 3) out = y1 @ w_out^T + b_out
        gemm_bias<<<gO, blk, 0, stream>>>(y1c, w_out, b_out, out + (long)s0 * OUT,
                                          Sc, (long)Sc * H, (long)H,
                                          (long)S * OUT, (long)OUT, OUT, H);
    }
}